// Round 1
// baseline (376.675 us; speedup 1.0000x reference)
//
#include <hip/hip_runtime.h>
#include <hip/hip_bf16.h>

#define V_N   40000
#define P_N   32
#define NTOT  (V_N * P_N)            // 1,280,000 positions in the BN batch
#define VXc   0.16f
#define VYc   0.16f
#define XOFF  0.08f                  // VX/2 + 0.0
#define YOFF  (-39.6f)               // VY/2 - 39.68
#define BN_EPS 1e-5f

// ---------------------------------------------------------------------------
// Kernel 1: accumulate S[9] = sum of features, M[45] = upper-tri of sum f f^T
// over all valid (v,p). One thread per voxel; wave-reduce; atomicAdd to ws.
// ---------------------------------------------------------------------------
__global__ __launch_bounds__(256) void stats_kernel(
    const float4* __restrict__ voxels,      // (V, P) float4
    const int*    __restrict__ npts_arr,    // (V,)
    const int*    __restrict__ coors,       // (V, 2)
    float*        __restrict__ stats)       // 54 floats, pre-zeroed
{
    const int v = blockIdx.x * 256 + threadIdx.x;

    float S[9];
    float M[45];
#pragma unroll
    for (int i = 0; i < 9; ++i)  S[i] = 0.f;
#pragma unroll
    for (int i = 0; i < 45; ++i) M[i] = 0.f;

    if (v < V_N) {
        const float4* vp = voxels + (size_t)v * P_N;
        const int   npts = npts_arr[v];
        const float cx = (float)coors[2 * v]     * VXc + XOFF;
        const float cy = (float)coors[2 * v + 1] * VYc + YOFF;

        // pass 1: sum xyz over ALL 32 points (reference does not mask here)
        float sx = 0.f, sy = 0.f, sz = 0.f;
#pragma unroll 8
        for (int p = 0; p < P_N; ++p) {
            float4 q = vp[p];
            sx += q.x; sy += q.y; sz += q.z;
        }
        const float inv = 1.f / (float)npts;
        const float mx = sx * inv, my = sy * inv, mz = sz * inv;

        // pass 2: accumulate moments over valid points only
        for (int p = 0; p < npts; ++p) {
            float4 q = vp[p];
            float f[9];
            f[0] = q.x; f[1] = q.y; f[2] = q.z; f[3] = q.w;
            f[4] = q.x - mx; f[5] = q.y - my; f[6] = q.z - mz;
            f[7] = q.x - cx; f[8] = q.y - cy;
            int k = 0;
#pragma unroll
            for (int i = 0; i < 9; ++i) {
                S[i] += f[i];
#pragma unroll
                for (int j = i; j < 9; ++j) {
                    M[k] = fmaf(f[i], f[j], M[k]);
                    ++k;
                }
            }
        }
    }

    // wave-level butterfly reduce each of the 54 accumulators, then one
    // atomicAdd per wave per entry (625 waves total -> light contention).
    const int lane = threadIdx.x & 63;
#pragma unroll
    for (int i = 0; i < 54; ++i) {
        float x = (i < 9) ? S[i] : M[i - 9];
#pragma unroll
        for (int m = 1; m < 64; m <<= 1)
            x += __shfl_xor(x, m, 64);
        if (lane == 0)
            atomicAdd(&stats[i], x);
    }
}

// ---------------------------------------------------------------------------
// Kernel 2: one wave per voxel. Each lane o (0..63) owns output channel o.
//   - derive BN scale/bias analytically from stats (uniform scalar loads)
//   - lanes 0..31 build the 9 features for their point into LDS
//   - all 64 lanes: max over valid p of scale*(f_p . W_o); fold in the
//     masked-position term (x=0) when npts<32; relu at the end.
// ---------------------------------------------------------------------------
__global__ __launch_bounds__(256) void pfn_kernel(
    const float4* __restrict__ voxels,
    const int*    __restrict__ npts_arr,
    const int*    __restrict__ coors,
    const float*  __restrict__ W,        // (64, 9) row-major
    const float*  __restrict__ gamma,    // (64,)
    const float*  __restrict__ beta,     // (64,)
    const float*  __restrict__ stats,    // 54 floats
    float*        __restrict__ out)      // (V, 64)
{
    __shared__ float fea[4][P_N][9];

    const int wib  = threadIdx.x >> 6;     // wave index in block (0..3)
    const int lane = threadIdx.x & 63;     // = output channel o
    const int v    = blockIdx.x * 4 + wib; // V_N = 40000 = 4 * 10000 exactly

    // ---- per-channel BN affine from the moment statistics ----
    float w[9];
#pragma unroll
    for (int c = 0; c < 9; ++c) w[c] = W[lane * 9 + c];

    const float invN = 1.f / (float)NTOT;
    float mean = 0.f;
#pragma unroll
    for (int c = 0; c < 9; ++c) mean = fmaf(w[c], stats[c], mean);
    mean *= invN;

    float ex2 = 0.f;
    {
        int k = 9;
#pragma unroll
        for (int i = 0; i < 9; ++i) {
#pragma unroll
            for (int j = i; j < 9; ++j) {
                const float coef = (i == j) ? 1.f : 2.f;
                ex2 = fmaf(coef * w[i] * w[j], stats[k], ex2);
                ++k;
            }
        }
    }
    ex2 *= invN;
    const float var   = ex2 - mean * mean;
    const float scale = gamma[lane] * rsqrtf(var + BN_EPS);
    const float bias  = fmaf(-mean, scale, beta[lane]);

    const int npts = npts_arr[v];

    // ---- phase A: features into LDS (lanes 0..31, one point each) ----
    if (lane < 32) {
        float4 q = voxels[(size_t)v * P_N + lane];
        float sx = q.x, sy = q.y, sz = q.z;
#pragma unroll
        for (int m = 1; m < 32; m <<= 1) {   // masks <=16 stay within lanes 0..31
            sx += __shfl_xor(sx, m, 64);
            sy += __shfl_xor(sy, m, 64);
            sz += __shfl_xor(sz, m, 64);
        }
        const float inv = 1.f / (float)npts;
        const float cx = (float)coors[2 * v]     * VXc + XOFF;
        const float cy = (float)coors[2 * v + 1] * VYc + YOFF;
        float* fp = &fea[wib][lane][0];
        fp[0] = q.x;            fp[1] = q.y;            fp[2] = q.z; fp[3] = q.w;
        fp[4] = q.x - sx * inv; fp[5] = q.y - sy * inv; fp[6] = q.z - sz * inv;
        fp[7] = q.x - cx;       fp[8] = q.y - cy;
    }
    __syncthreads();   // safe cross-lane LDS visibility (4 waves, all reach it)

    // ---- phase B: per-channel max over valid points ----
    float macc = -3.4e38f;
    for (int p = 0; p < npts; ++p) {
        const float* fp = &fea[wib][p][0];
        float d = 0.f;
#pragma unroll
        for (int c = 0; c < 9; ++c) d = fmaf(fp[c], w[c], d);
        macc = fmaxf(macc, d * scale);
    }
    if (npts < P_N) macc = fmaxf(macc, 0.f);  // masked positions: x = 0

    out[(size_t)v * 64 + lane] = fmaxf(macc + bias, 0.f);
}

// ---------------------------------------------------------------------------
extern "C" void kernel_launch(void* const* d_in, const int* in_sizes, int n_in,
                              void* d_out, int out_size, void* d_ws, size_t ws_size,
                              hipStream_t stream)
{
    const float4* voxels = (const float4*)d_in[0];
    const int*    npts   = (const int*)d_in[1];
    const int*    coors  = (const int*)d_in[2];
    const float*  W      = (const float*)d_in[3];
    const float*  gamma  = (const float*)d_in[4];
    const float*  beta   = (const float*)d_in[5];
    float*        out    = (float*)d_out;
    float*        stats  = (float*)d_ws;   // 54 floats

    hipMemsetAsync(stats, 0, 54 * sizeof(float), stream);
    stats_kernel<<<(V_N + 255) / 256, 256, 0, stream>>>(voxels, npts, coors, stats);
    pfn_kernel<<<V_N / 4, 256, 0, stream>>>(voxels, npts, coors, W, gamma, beta,
                                            stats, out);
}

// Round 2
// 162.502 us; speedup vs baseline: 2.3180x; 2.3180x over previous
//
#include <hip/hip_runtime.h>
#include <hip/hip_bf16.h>

#define V_N   40000
#define P_N   32
#define NTOT  (V_N * P_N)            // BN batch positions
#define VXc   0.16f
#define VYc   0.16f
#define XOFF  0.08f                  // VX/2 + 0.0
#define YOFF  (-39.6f)               // VY/2 - 39.68
#define BN_EPS 1e-5f

#define SBLK  768                    // stats blocks (3072 waves)
#define PBLK  2500                   // pfn blocks: 10000 waves x 4 voxels = 40000

// ---------------------------------------------------------------------------
// Kernel 1: S[9] = sum f, M[45] = upper-tri sum f f^T over valid (v,p).
// (v,p)-parallel: each wave handles 2 voxels/iter (lane&31 = point, lane>>5 =
// which voxel). Coalesced 1 KiB/wave loads. Per-voxel xyz sum via intra-half
// butterfly (masks 1..16 stay inside each 32-lane half).
// ---------------------------------------------------------------------------
__global__ __launch_bounds__(256) void stats_kernel(
    const float4* __restrict__ voxels,
    const int*    __restrict__ npts_arr,
    const int*    __restrict__ coors,
    float*        __restrict__ stats)       // 54 floats, pre-zeroed
{
    const int lane = threadIdx.x & 63;
    const int p    = lane & 31;
    const int half = lane >> 5;
    const int gw   = (blockIdx.x * 256 + threadIdx.x) >> 6;
    const int nw   = (gridDim.x * 256) >> 6;

    float S[9], M[45];
#pragma unroll
    for (int i = 0; i < 9; ++i)  S[i] = 0.f;
#pragma unroll
    for (int i = 0; i < 45; ++i) M[i] = 0.f;

    for (int vb = gw * 2; vb < V_N; vb += nw * 2) {
        const int v = vb + half;                       // V_N even -> in range
        float4 q = voxels[(size_t)v * P_N + p];

        // per-voxel xyz sum over ALL 32 points (reference does not mask here)
        float sx = q.x, sy = q.y, sz = q.z;
#pragma unroll
        for (int m = 1; m < 32; m <<= 1) {
            sx += __shfl_xor(sx, m, 64);
            sy += __shfl_xor(sy, m, 64);
            sz += __shfl_xor(sz, m, 64);
        }
        const int   npts = npts_arr[v];
        const float inv  = 1.f / (float)npts;
        const float cx = (float)coors[2 * v]     * VXc + XOFF;
        const float cy = (float)coors[2 * v + 1] * VYc + YOFF;

        if (p < npts) {
            float f[9];
            f[0] = q.x; f[1] = q.y; f[2] = q.z; f[3] = q.w;
            f[4] = q.x - sx * inv; f[5] = q.y - sy * inv; f[6] = q.z - sz * inv;
            f[7] = q.x - cx;       f[8] = q.y - cy;
            int k = 0;
#pragma unroll
            for (int i = 0; i < 9; ++i) {
                S[i] += f[i];
#pragma unroll
                for (int j = i; j < 9; ++j) { M[k] = fmaf(f[i], f[j], M[k]); ++k; }
            }
        }
    }

    // full 64-lane butterfly (sums both halves = both voxel streams)
#pragma unroll
    for (int i = 0; i < 9; ++i)
#pragma unroll
        for (int m = 1; m < 64; m <<= 1) S[i] += __shfl_xor(S[i], m, 64);
#pragma unroll
    for (int i = 0; i < 45; ++i)
#pragma unroll
        for (int m = 1; m < 64; m <<= 1) M[i] += __shfl_xor(M[i], m, 64);

    // block-level reduce (4 waves) then 54 parallel-lane atomics per block
    __shared__ float red[4][54];
    const int wib = threadIdx.x >> 6;
    if (lane == 0) {
#pragma unroll
        for (int i = 0; i < 9;  ++i) red[wib][i]     = S[i];
#pragma unroll
        for (int i = 0; i < 45; ++i) red[wib][9 + i] = M[i];
    }
    __syncthreads();
    if (threadIdx.x < 54) {
        float s = red[0][threadIdx.x] + red[1][threadIdx.x]
                + red[2][threadIdx.x] + red[3][threadIdx.x];
        atomicAdd(&stats[threadIdx.x], s);
    }
}

// ---------------------------------------------------------------------------
// Kernel 2: one wave per voxel iter (4 voxels per wave). Lane o = out channel.
// Folded affine: scale*(f_p . w_o) = q_p . a_o + b_{v,o} with a_o per-lane
// constants (scale folded in) and b point-invariant -> added after the max.
// Inner loop: 1 ds_read_b128 broadcast + 4 FMA + sel/max per point.
// ---------------------------------------------------------------------------
__global__ __launch_bounds__(256) void pfn_kernel(
    const float4* __restrict__ voxels,
    const int*    __restrict__ npts_arr,
    const int*    __restrict__ coors,
    const float*  __restrict__ W,        // (64, 9) row-major
    const float*  __restrict__ gamma,
    const float*  __restrict__ beta,
    const float*  __restrict__ stats,    // 54 floats
    float*        __restrict__ out)      // (V, 64)
{
    __shared__ float4 sq[4][P_N];
    const int wib  = threadIdx.x >> 6;
    const int lane = threadIdx.x & 63;
    const int pl   = lane & 31;

    // ---- BN affine from moment statistics (once per wave) ----
    float w[9];
#pragma unroll
    for (int c = 0; c < 9; ++c) w[c] = W[lane * 9 + c];

    const float invN = 1.f / (float)NTOT;
    float mean = 0.f;
#pragma unroll
    for (int c = 0; c < 9; ++c) mean = fmaf(w[c], stats[c], mean);
    mean *= invN;

    float ex2 = 0.f;
    {
        int k = 9;
#pragma unroll
        for (int i = 0; i < 9; ++i)
#pragma unroll
            for (int j = i; j < 9; ++j) {
                const float coef = (i == j) ? 1.f : 2.f;
                ex2 = fmaf(coef * w[i] * w[j], stats[k], ex2);
                ++k;
            }
    }
    ex2 *= invN;
    const float var   = ex2 - mean * mean;
    const float scale = gamma[lane] * rsqrtf(var + BN_EPS);
    const float bias  = fmaf(-mean, scale, beta[lane]);

    // folded weights, scale pre-multiplied
    const float a0 = (w[0] + w[4] + w[7]) * scale;
    const float a1 = (w[1] + w[5] + w[8]) * scale;
    const float a2 = (w[2] + w[6]) * scale;
    const float a3 =  w[3] * scale;
    const float u4 = w[4] * scale, u5 = w[5] * scale, u6 = w[6] * scale;
    const float u7 = w[7] * scale, u8 = w[8] * scale;

    const int gw = (blockIdx.x * 256 + threadIdx.x) >> 6;   // 0..9999

#pragma unroll
    for (int it = 0; it < 4; ++it) {
        const int v = gw * 4 + it;

        // both halves load the same 512B (L1 dedups); each half then holds
        // the full 32-point sum after masks 1..16
        float4 q = voxels[(size_t)v * P_N + pl];
        float sx = q.x, sy = q.y, sz = q.z;
#pragma unroll
        for (int m = 1; m < 32; m <<= 1) {
            sx += __shfl_xor(sx, m, 64);
            sy += __shfl_xor(sy, m, 64);
            sz += __shfl_xor(sz, m, 64);
        }
        if (lane < 32) sq[wib][lane] = q;
        __builtin_amdgcn_wave_barrier();

        const int   npts = npts_arr[v];
        const float inv  = 1.f / (float)npts;
        const float mx = sx * inv, my = sy * inv, mz = sz * inv;
        const float cx = (float)coors[2 * v]     * VXc + XOFF;
        const float cy = (float)coors[2 * v + 1] * VYc + YOFF;
        const float b  = -(mx * u4 + my * u5 + mz * u6 + cx * u7 + cy * u8);

        float macc = -3.4e38f;
#pragma unroll
        for (int p = 0; p < P_N; ++p) {
            float4 t = sq[wib][p];                       // broadcast read
            float d = fmaf(t.x, a0, fmaf(t.y, a1, fmaf(t.z, a2, t.w * a3)));
            macc = (p < npts) ? fmaxf(macc, d) : macc;   // uniform select
        }
        float mfin = macc + b;
        if (npts < P_N) mfin = fmaxf(mfin, 0.f);         // masked rows: x=0
        out[(size_t)v * 64 + lane] = fmaxf(mfin + bias, 0.f);
        __builtin_amdgcn_wave_barrier();
    }
}

// ---------------------------------------------------------------------------
extern "C" void kernel_launch(void* const* d_in, const int* in_sizes, int n_in,
                              void* d_out, int out_size, void* d_ws, size_t ws_size,
                              hipStream_t stream)
{
    const float4* voxels = (const float4*)d_in[0];
    const int*    npts   = (const int*)d_in[1];
    const int*    coors  = (const int*)d_in[2];
    const float*  W      = (const float*)d_in[3];
    const float*  gamma  = (const float*)d_in[4];
    const float*  beta   = (const float*)d_in[5];
    float*        out    = (float*)d_out;
    float*        stats  = (float*)d_ws;   // 54 floats

    hipMemsetAsync(stats, 0, 54 * sizeof(float), stream);
    stats_kernel<<<SBLK, 256, 0, stream>>>(voxels, npts, coors, stats);
    pfn_kernel<<<PBLK, 256, 0, stream>>>(voxels, npts, coors, W, gamma, beta,
                                         stats, out);
}